// Round 2
// baseline (323.385 us; speedup 1.0000x reference)
//
#include <hip/hip_runtime.h>
#include <hip/hip_bf16.h>

#define B_ 4
#define N_ 4096
#define D_ 128
#define KSEG 8
#define QSEG 8

typedef __bf16 bf16x8 __attribute__((ext_vector_type(8)));
typedef float f32x4 __attribute__((ext_vector_type(4)));

// alpha = log2(e) / sqrt(128), folded into Qp at conversion time
#define ALPHA 0.12752361680972262f

// ws layout (all fragment-linear packed, 16 B per (tile,frag,lane) chunk):
//   Qp : bf16 [B][256 qstep][4 f][64 lane][8]   @ 0      (4 MiB, alpha-scaled)
//   Kp : bf16 [B][128 kb][8 slot=f*2+ab][64][8] @ 4 MiB  (permuted-key frag order)
//   Vp : bf16 [B][128 kb][8 ds][64][8]          @ 8 MiB  (1/l folded in place)
//   l    : f32 [B][N]                           @ 12 MiB
#define OFF_KP   (4u << 20)
#define OFF_VP   (8u << 20)
#define OFF_L    (12u << 20)

// direct global->LDS DMA, 16 B per lane; LDS dest is wave-uniform base + lane*16
__device__ __forceinline__ void gload_lds16(const void* g, void* s) {
    __builtin_amdgcn_global_load_lds(
        (const __attribute__((address_space(1))) void*)g,
        (__attribute__((address_space(3))) void*)s, 16, 0, 0);
}

// ---------------------------------------------------------------------------
// Kernel A: pack Q*alpha, K (permuted key order), V-transpose into fragment-
// linear layouts. UNCHANGED.
// ---------------------------------------------------------------------------
__global__ __launch_bounds__(256) void cvt_kernel(
    const float* __restrict__ q, const float* __restrict__ k,
    const float* __restrict__ v,
    __bf16* __restrict__ qp, __bf16* __restrict__ kp, __bf16* __restrict__ vp)
{
    __shared__ float vl[32 * 129];   // 16.5 KiB (V section only)

    int bid = blockIdx.x;
    int tid = threadIdx.x;
    if (bid < 2048) {
        int g = (bid & 1023) * 256 + tid;   // 0..262143 within section
        int lane = g & 63;
        int l15 = lane & 15, quad = lane >> 4;
        if (bid < 1024) {
            int f = (g >> 6) & 3;
            int qstep = (g >> 8) & 255;
            int b = g >> 16;
            const float* src = q + ((size_t)(b * N_ + qstep * 16 + l15) * D_ + (f * 4 + quad) * 8);
            float4 x0 = *(const float4*)src;
            float4 x1 = *(const float4*)(src + 4);
            bf16x8 y;
            y[0] = (__bf16)(x0.x * ALPHA); y[1] = (__bf16)(x0.y * ALPHA);
            y[2] = (__bf16)(x0.z * ALPHA); y[3] = (__bf16)(x0.w * ALPHA);
            y[4] = (__bf16)(x1.x * ALPHA); y[5] = (__bf16)(x1.y * ALPHA);
            y[6] = (__bf16)(x1.z * ALPHA); y[7] = (__bf16)(x1.w * ALPHA);
            ((bf16x8*)qp)[g] = y;
        } else {
            int slot = (g >> 6) & 7;
            int kb = (g >> 9) & 127;
            int b = g >> 16;
            int f = slot >> 1, ab = slot & 1;
            int row = kb * 32 + (l15 >> 2) * 8 + (l15 & 3) + ab * 4;
            const float* src = k + ((size_t)(b * N_ + row) * D_ + (f * 4 + quad) * 8);
            float4 x0 = *(const float4*)src;
            float4 x1 = *(const float4*)(src + 4);
            bf16x8 y;
            y[0] = (__bf16)x0.x; y[1] = (__bf16)x0.y; y[2] = (__bf16)x0.z; y[3] = (__bf16)x0.w;
            y[4] = (__bf16)x1.x; y[5] = (__bf16)x1.y; y[6] = (__bf16)x1.z; y[7] = (__bf16)x1.w;
            ((bf16x8*)kp)[g] = y;
        }
    } else {
        int vb = bid - 2048;                // 0..511: one (b, kb) tile
        int b = vb >> 7, kb = vb & 127;
        const float4* src = (const float4*)(v + (size_t)(b * N_ + kb * 32) * D_);
#pragma unroll
        for (int rep = 0; rep < 4; ++rep) {
            int i = rep * 256 + tid;
            int row = i >> 5, c4 = i & 31;
            float4 x = src[row * 32 + c4];
            float* dst = &vl[row * 129 + c4 * 4];
            dst[0] = x.x; dst[1] = x.y; dst[2] = x.z; dst[3] = x.w;
        }
        __syncthreads();
#pragma unroll
        for (int rep = 0; rep < 2; ++rep) {
            int ci = rep * 256 + tid;       // 0..511
            int ds = ci >> 6, ln = ci & 63;
            int quad = ln >> 4, l15 = ln & 15;
            bf16x8 y;
#pragma unroll
            for (int j = 0; j < 8; ++j)
                y[j] = (__bf16)vl[(quad * 8 + j) * 129 + ds * 16 + l15];
            ((bf16x8*)vp)[(((size_t)(b * 128 + kb) * 8) + ds) * 64 + ln] = y;
        }
    }
}

// ---------------------------------------------------------------------------
// Kernel B: column stats. Q-tile staging via global_load_lds (wave w DMAs
// q-step (t*4+w)'s 4 chunks directly into LDS; no staging regs, no ds_write).
// ---------------------------------------------------------------------------
__global__ __launch_bounds__(256, 4) void stats_kernel(
    const __bf16* __restrict__ qp, const __bf16* __restrict__ kp,
    float* __restrict__ l)
{
    __shared__ __bf16 lds[2][16 * 512];   // 2 x 16 KiB

    int idx = blockIdx.x;
    int qseg = idx & (QSEG - 1);
    int kb4 = (idx >> 3) & 31;
    int b = idx >> 8;
    int w = threadIdx.x >> 6;
    int lane = threadIdx.x & 63;
    int quad = lane >> 4, l15 = lane & 15;
    int kb = kb4 * 4 + w;

    const bf16x8* kc = (const bf16x8*)kp;
    const bf16x8* qc8 = (const bf16x8*)qp;

    bf16x8 af[2][4];
#pragma unroll
    for (int ab = 0; ab < 2; ++ab)
#pragma unroll
        for (int f = 0; f < 4; ++f)
            af[ab][f] = kc[(((size_t)(b * 128 + kb) * 8) + f * 2 + ab) * 64 + lane];

    int qs0 = qseg * 32;                  // 32 q-steps per segment, 8 iters of 4

    // prologue: DMA tile 0
#pragma unroll
    for (int f = 0; f < 4; ++f)
        gload_lds16(&qc8[((size_t)(b * 256 + qs0 + w) * 4 + f) * 64 + lane],
                    &lds[0][(w * 4 + f) * 512]);
    __syncthreads();

    float ps[8];
#pragma unroll
    for (int s = 0; s < 8; ++s) ps[s] = 0.f;

    for (int t = 0; t < 8; ++t) {
        __bf16* buf = &lds[t & 1][0];
        if (t + 1 < 8) {
            __bf16* nbuf = &lds[(t + 1) & 1][0];
#pragma unroll
            for (int f = 0; f < 4; ++f)
                gload_lds16(&qc8[((size_t)(b * 256 + qs0 + (t + 1) * 4 + w) * 4 + f) * 64 + lane],
                            &nbuf[(w * 4 + f) * 512]);
        }
#pragma unroll
        for (int j = 0; j < 4; ++j) {
            bf16x8 qf[4];
#pragma unroll
            for (int f = 0; f < 4; ++f)
                qf[f] = *(const bf16x8*)(buf + (j * 4 + f) * 512 + lane * 8);
#pragma unroll
            for (int ab = 0; ab < 2; ++ab) {
                f32x4 acc = {0.f, 0.f, 0.f, 0.f};
#pragma unroll
                for (int f = 0; f < 4; ++f)
                    acc = __builtin_amdgcn_mfma_f32_16x16x32_bf16(af[ab][f], qf[f], acc, 0, 0, 0);
#pragma unroll
                for (int r = 0; r < 4; ++r)
                    ps[ab * 4 + r] += __builtin_amdgcn_exp2f(acc[r]);
            }
        }
        __syncthreads();                  // next tile landed; buf free for t+2
    }
#pragma unroll
    for (int m = 1; m <= 8; m <<= 1)
#pragma unroll
        for (int s = 0; s < 8; ++s)
            ps[s] += __shfl_xor(ps[s], m, 64);
    if (l15 == 0) {
        // permuted C rows: key = kb*32 + quad*8 + ab*4 + r
        float* dst = l + (size_t)b * N_ + kb * 32 + quad * 8;
#pragma unroll
        for (int ab = 0; ab < 2; ++ab)
#pragma unroll
            for (int r = 0; r < 4; ++r)
                atomicAdd(dst + ab * 4 + r, ps[ab * 4 + r]);
    }
}

// ---------------------------------------------------------------------------
// Kernel C2: Vp chunk (b,kb,ds,lane) *= 1/l[...]  UNCHANGED.
// ---------------------------------------------------------------------------
__global__ __launch_bounds__(256) void scalev_kernel(
    const float* __restrict__ l, __bf16* __restrict__ vp)
{
    int i = blockIdx.x * 256 + threadIdx.x;  // chunk index, 262144 total
    int lane = i & 63;
    int kb = (i >> 9) & 127;
    int b = i >> 16;
    int quad = lane >> 4;
    int k0 = kb * 32 + quad * 8;
    const float* lp = l + (size_t)b * N_ + k0;
    float4 a = *(const float4*)lp;
    float4 c = *(const float4*)(lp + 4);
    float r0 = __builtin_amdgcn_rcpf(a.x), r1 = __builtin_amdgcn_rcpf(a.y);
    float r2 = __builtin_amdgcn_rcpf(a.z), r3 = __builtin_amdgcn_rcpf(a.w);
    float r4 = __builtin_amdgcn_rcpf(c.x), r5 = __builtin_amdgcn_rcpf(c.y);
    float r6 = __builtin_amdgcn_rcpf(c.z), r7 = __builtin_amdgcn_rcpf(c.w);
    bf16x8 v = ((const bf16x8*)vp)[i];
    bf16x8 o;
    o[0] = (__bf16)((float)v[0] * r0); o[1] = (__bf16)((float)v[1] * r1);
    o[2] = (__bf16)((float)v[2] * r2); o[3] = (__bf16)((float)v[3] * r3);
    o[4] = (__bf16)((float)v[4] * r4); o[5] = (__bf16)((float)v[5] * r5);
    o[6] = (__bf16)((float)v[6] * r6); o[7] = (__bf16)((float)v[7] * r7);
    ((bf16x8*)vp)[i] = o;
}

// ---------------------------------------------------------------------------
// Kernel D: attention.
//  - s=4: each wave owns 64 q rows (bq[4][4] in regs, oacc[4][8] = 128 VGPR),
//    doubling MFMA per LDS tile read (64 MFMA vs 16 ds_read per iter).
//  - K/V tile staged via global_load_lds DMA (no staging regs, no ds_write);
//    tile t+1 issued before computing tile t, drained by the closing barrier.
//  - KSEG=8, grid 512 = (b,seg,qtile), XCD-bijective swizzle so the 16
//    q-tile blocks of each (b,seg) share one XCD's L2 (256 KB K+V slice).
//  - epilogue: fp32 atomicAdd directly into out (out pre-zeroed); no part
//    buffer, no reduce kernel.
// ---------------------------------------------------------------------------
__global__ __launch_bounds__(256, 2) void attn_kernel(
    const __bf16* __restrict__ qp, const __bf16* __restrict__ kp,
    const __bf16* __restrict__ vp, float* __restrict__ out)
{
    __shared__ __bf16 lds[2][16 * 512];   // 2 x 16 KiB: chunks 0-7 K, 8-15 V

    // bijective swizzle: blocks with same (b,seg) land on one XCD (bid%8)
    int x = blockIdx.x;
    int xcd = x & 7;
    int i = x >> 3;                       // 0..63
    int group = xcd * 4 + (i & 3);        // 0..31 = (b,seg)
    int qtile = i >> 2;                   // 0..15 (256 q each)
    int b = group >> 3;
    int seg = group & 7;

    int w = threadIdx.x >> 6;
    int lane = threadIdx.x & 63;
    int quad = lane >> 4, l15 = lane & 15;

    const bf16x8* qc8 = (const bf16x8*)qp;
    const bf16x8* kc = (const bf16x8*)kp;
    const bf16x8* vc = (const bf16x8*)vp;

    int q0w = qtile * 256 + w * 64;       // this wave's 64 q rows
    int qstep0 = qtile * 16 + w * 4;
    bf16x8 bq[4][4];
#pragma unroll
    for (int s = 0; s < 4; ++s)
#pragma unroll
        for (int f = 0; f < 4; ++f)
            bq[s][f] = qc8[((size_t)(b * 256 + qstep0 + s) * 4 + f) * 64 + lane];

    f32x4 oacc[4][8];
#pragma unroll
    for (int s = 0; s < 4; ++s)
#pragma unroll
        for (int d = 0; d < 8; ++d) oacc[s][d] = (f32x4){0.f, 0.f, 0.f, 0.f};

    int kb0 = seg * 16;

    // prologue: DMA tile 0 (wave w stages chunks w*4..w*4+3)
#pragma unroll
    for (int ii = 0; ii < 4; ++ii) {
        int c = w * 4 + ii;
        const bf16x8* src = (c < 8) ? &kc[(((size_t)(b * 128 + kb0) * 8) + c) * 64 + lane]
                                    : &vc[(((size_t)(b * 128 + kb0) * 8) + (c - 8)) * 64 + lane];
        gload_lds16(src, &lds[0][c * 512]);
    }
    __syncthreads();

    for (int t = 0; t < 16; ++t) {
        __bf16* buf = &lds[t & 1][0];
        if (t + 1 < 16) {
            int kbn = kb0 + t + 1;
            __bf16* nbuf = &lds[(t + 1) & 1][0];
#pragma unroll
            for (int ii = 0; ii < 4; ++ii) {
                int c = w * 4 + ii;
                const bf16x8* src = (c < 8) ? &kc[(((size_t)(b * 128 + kbn) * 8) + c) * 64 + lane]
                                            : &vc[(((size_t)(b * 128 + kbn) * 8) + (c - 8)) * 64 + lane];
                gload_lds16(src, &nbuf[c * 512]);
            }
        }

        // QK^T + exp, per ab-half to cap register transients
        bf16x8 pb[4];
#pragma unroll
        for (int ab = 0; ab < 2; ++ab) {
            bf16x8 ak[4];
#pragma unroll
            for (int f = 0; f < 4; ++f)
                ak[f] = *(const bf16x8*)(buf + (f * 2 + ab) * 512 + lane * 8);
#pragma unroll
            for (int s = 0; s < 4; ++s) {
                f32x4 acc = {0.f, 0.f, 0.f, 0.f};
#pragma unroll
                for (int f = 0; f < 4; ++f)
                    acc = __builtin_amdgcn_mfma_f32_16x16x32_bf16(ak[f], bq[s][f], acc, 0, 0, 0);
#pragma unroll
                for (int r = 0; r < 4; ++r)
                    pb[s][ab * 4 + r] = (__bf16)__builtin_amdgcn_exp2f(acc[r]);
            }
        }
        // PV
#pragma unroll
        for (int ds = 0; ds < 8; ++ds) {
            bf16x8 vf = *(const bf16x8*)(buf + (8 + ds) * 512 + lane * 8);
#pragma unroll
            for (int s = 0; s < 4; ++s)
                oacc[s][ds] = __builtin_amdgcn_mfma_f32_16x16x32_bf16(
                    vf, pb[s], oacc[s][ds], 0, 0, 0);
        }
        __syncthreads();                  // tile t+1 landed; buf free for t+2
    }

    float* op = out + ((size_t)b * N_ + q0w) * D_;
#pragma unroll
    for (int s = 0; s < 4; ++s)
#pragma unroll
        for (int ds = 0; ds < 8; ++ds) {
            float* p = op + (size_t)(s * 16 + l15) * D_ + ds * 16 + quad * 4;
            atomicAdd(p + 0, oacc[s][ds][0]);
            atomicAdd(p + 1, oacc[s][ds][1]);
            atomicAdd(p + 2, oacc[s][ds][2]);
            atomicAdd(p + 3, oacc[s][ds][3]);
        }
}

extern "C" void kernel_launch(void* const* d_in, const int* in_sizes, int n_in,
                              void* d_out, int out_size, void* d_ws, size_t ws_size,
                              hipStream_t stream) {
    const float* q = (const float*)d_in[0];
    const float* k = (const float*)d_in[1];
    const float* v = (const float*)d_in[2];
    float* out = (float*)d_out;
    char* ws = (char*)d_ws;
    __bf16* qp = (__bf16*)(ws);
    __bf16* kp = (__bf16*)(ws + OFF_KP);
    __bf16* vp = (__bf16*)(ws + OFF_VP);
    float* l    = (float*)(ws + OFF_L);

    hipLaunchKernelGGL(cvt_kernel, dim3(2560), dim3(256), 0, stream, q, k, v, qp, kp, vp);
    hipMemsetAsync(l, 0, (size_t)B_ * N_ * sizeof(float), stream);
    hipMemsetAsync(out, 0, (size_t)B_ * N_ * D_ * sizeof(float), stream);
    hipLaunchKernelGGL(stats_kernel, dim3(B_ * 32 * QSEG), dim3(256), 0, stream, qp, kp, l);
    hipLaunchKernelGGL(scalev_kernel, dim3(1024), dim3(256), 0, stream, l, vp);
    hipLaunchKernelGGL(attn_kernel, dim3(B_ * 16 * KSEG), dim3(256), 0, stream, qp, kp, vp, out);
}

// Round 3
// 149.402 us; speedup vs baseline: 2.1645x; 2.1645x over previous
//
#include <hip/hip_runtime.h>
#include <hip/hip_bf16.h>

#define B_ 4
#define N_ 4096
#define D_ 128
#define KSEG 8
#define QSEG 8

typedef __bf16 bf16x8 __attribute__((ext_vector_type(8)));
typedef float f32x4 __attribute__((ext_vector_type(4)));

// alpha = log2(e) / sqrt(128), folded into Qp at conversion time
#define ALPHA 0.12752361680972262f

// ws layout (all fragment-linear packed, 16 B per (tile,frag,lane) chunk):
//   Qp : bf16 [B][256 qstep][4 f][64 lane][8]   @ 0      (4 MiB, alpha-scaled)
//   Kp : bf16 [B][128 kb][8 slot=f*2+ab][64][8] @ 4 MiB  (permuted-key frag order)
//   Vp : bf16 [B][128 kb][8 ds][64][8]          @ 8 MiB  (1/l folded in place)
//   l    : f32 [B][N]                           @ 12 MiB
//   part : f32 [KSEG][B][N][D]                  @ 13 MiB (64 MiB, KSEG=8)
#define OFF_KP   (4u << 20)
#define OFF_VP   (8u << 20)
#define OFF_L    (12u << 20)
#define OFF_PART (13u << 20)

// direct global->LDS DMA, 16 B per lane; LDS dest is wave-uniform base + lane*16
__device__ __forceinline__ void gload_lds16(const void* g, void* s) {
    __builtin_amdgcn_global_load_lds(
        (const __attribute__((address_space(1))) void*)g,
        (__attribute__((address_space(3))) void*)s, 16, 0, 0);
}

// ---------------------------------------------------------------------------
// Kernel A: pack Q*alpha, K (permuted key order), V-transpose into fragment-
// linear layouts. UNCHANGED.
// ---------------------------------------------------------------------------
__global__ __launch_bounds__(256) void cvt_kernel(
    const float* __restrict__ q, const float* __restrict__ k,
    const float* __restrict__ v,
    __bf16* __restrict__ qp, __bf16* __restrict__ kp, __bf16* __restrict__ vp)
{
    __shared__ float vl[32 * 129];   // 16.5 KiB (V section only)

    int bid = blockIdx.x;
    int tid = threadIdx.x;
    if (bid < 2048) {
        int g = (bid & 1023) * 256 + tid;   // 0..262143 within section
        int lane = g & 63;
        int l15 = lane & 15, quad = lane >> 4;
        if (bid < 1024) {
            int f = (g >> 6) & 3;
            int qstep = (g >> 8) & 255;
            int b = g >> 16;
            const float* src = q + ((size_t)(b * N_ + qstep * 16 + l15) * D_ + (f * 4 + quad) * 8);
            float4 x0 = *(const float4*)src;
            float4 x1 = *(const float4*)(src + 4);
            bf16x8 y;
            y[0] = (__bf16)(x0.x * ALPHA); y[1] = (__bf16)(x0.y * ALPHA);
            y[2] = (__bf16)(x0.z * ALPHA); y[3] = (__bf16)(x0.w * ALPHA);
            y[4] = (__bf16)(x1.x * ALPHA); y[5] = (__bf16)(x1.y * ALPHA);
            y[6] = (__bf16)(x1.z * ALPHA); y[7] = (__bf16)(x1.w * ALPHA);
            ((bf16x8*)qp)[g] = y;
        } else {
            int slot = (g >> 6) & 7;
            int kb = (g >> 9) & 127;
            int b = g >> 16;
            int f = slot >> 1, ab = slot & 1;
            int row = kb * 32 + (l15 >> 2) * 8 + (l15 & 3) + ab * 4;
            const float* src = k + ((size_t)(b * N_ + row) * D_ + (f * 4 + quad) * 8);
            float4 x0 = *(const float4*)src;
            float4 x1 = *(const float4*)(src + 4);
            bf16x8 y;
            y[0] = (__bf16)x0.x; y[1] = (__bf16)x0.y; y[2] = (__bf16)x0.z; y[3] = (__bf16)x0.w;
            y[4] = (__bf16)x1.x; y[5] = (__bf16)x1.y; y[6] = (__bf16)x1.z; y[7] = (__bf16)x1.w;
            ((bf16x8*)kp)[g] = y;
        }
    } else {
        int vb = bid - 2048;                // 0..511: one (b, kb) tile
        int b = vb >> 7, kb = vb & 127;
        const float4* src = (const float4*)(v + (size_t)(b * N_ + kb * 32) * D_);
#pragma unroll
        for (int rep = 0; rep < 4; ++rep) {
            int i = rep * 256 + tid;
            int row = i >> 5, c4 = i & 31;
            float4 x = src[row * 32 + c4];
            float* dst = &vl[row * 129 + c4 * 4];
            dst[0] = x.x; dst[1] = x.y; dst[2] = x.z; dst[3] = x.w;
        }
        __syncthreads();
#pragma unroll
        for (int rep = 0; rep < 2; ++rep) {
            int ci = rep * 256 + tid;       // 0..511
            int ds = ci >> 6, ln = ci & 63;
            int quad = ln >> 4, l15 = ln & 15;
            bf16x8 y;
#pragma unroll
            for (int j = 0; j < 8; ++j)
                y[j] = (__bf16)vl[(quad * 8 + j) * 129 + ds * 16 + l15];
            ((bf16x8*)vp)[(((size_t)(b * 128 + kb) * 8) + ds) * 64 + ln] = y;
        }
    }
}

// ---------------------------------------------------------------------------
// Kernel B: column stats. Q-tile staging via global_load_lds.
// ---------------------------------------------------------------------------
__global__ __launch_bounds__(256, 4) void stats_kernel(
    const __bf16* __restrict__ qp, const __bf16* __restrict__ kp,
    float* __restrict__ l)
{
    __shared__ __bf16 lds[2][16 * 512];   // 2 x 16 KiB

    int idx = blockIdx.x;
    int qseg = idx & (QSEG - 1);
    int kb4 = (idx >> 3) & 31;
    int b = idx >> 8;
    int w = threadIdx.x >> 6;
    int lane = threadIdx.x & 63;
    int quad = lane >> 4, l15 = lane & 15;
    int kb = kb4 * 4 + w;

    const bf16x8* kc = (const bf16x8*)kp;
    const bf16x8* qc8 = (const bf16x8*)qp;

    bf16x8 af[2][4];
#pragma unroll
    for (int ab = 0; ab < 2; ++ab)
#pragma unroll
        for (int f = 0; f < 4; ++f)
            af[ab][f] = kc[(((size_t)(b * 128 + kb) * 8) + f * 2 + ab) * 64 + lane];

    int qs0 = qseg * 32;                  // 32 q-steps per segment, 8 iters of 4

    // prologue: DMA tile 0
#pragma unroll
    for (int f = 0; f < 4; ++f)
        gload_lds16(&qc8[((size_t)(b * 256 + qs0 + w) * 4 + f) * 64 + lane],
                    &lds[0][(w * 4 + f) * 512]);
    __syncthreads();

    float ps[8];
#pragma unroll
    for (int s = 0; s < 8; ++s) ps[s] = 0.f;

    for (int t = 0; t < 8; ++t) {
        __bf16* buf = &lds[t & 1][0];
        if (t + 1 < 8) {
            __bf16* nbuf = &lds[(t + 1) & 1][0];
#pragma unroll
            for (int f = 0; f < 4; ++f)
                gload_lds16(&qc8[((size_t)(b * 256 + qs0 + (t + 1) * 4 + w) * 4 + f) * 64 + lane],
                            &nbuf[(w * 4 + f) * 512]);
        }
#pragma unroll
        for (int j = 0; j < 4; ++j) {
            bf16x8 qf[4];
#pragma unroll
            for (int f = 0; f < 4; ++f)
                qf[f] = *(const bf16x8*)(buf + (j * 4 + f) * 512 + lane * 8);
#pragma unroll
            for (int ab = 0; ab < 2; ++ab) {
                f32x4 acc = {0.f, 0.f, 0.f, 0.f};
#pragma unroll
                for (int f = 0; f < 4; ++f)
                    acc = __builtin_amdgcn_mfma_f32_16x16x32_bf16(af[ab][f], qf[f], acc, 0, 0, 0);
#pragma unroll
                for (int r = 0; r < 4; ++r)
                    ps[ab * 4 + r] += __builtin_amdgcn_exp2f(acc[r]);
            }
        }
        __syncthreads();                  // next tile landed; buf free for t+2
    }
#pragma unroll
    for (int m = 1; m <= 8; m <<= 1)
#pragma unroll
        for (int s = 0; s < 8; ++s)
            ps[s] += __shfl_xor(ps[s], m, 64);
    if (l15 == 0) {
        // permuted C rows: key = kb*32 + quad*8 + ab*4 + r
        float* dst = l + (size_t)b * N_ + kb * 32 + quad * 8;
#pragma unroll
        for (int ab = 0; ab < 2; ++ab)
#pragma unroll
            for (int r = 0; r < 4; ++r)
                atomicAdd(dst + ab * 4 + r, ps[ab * 4 + r]);
    }
}

// ---------------------------------------------------------------------------
// Kernel C2: Vp chunk (b,kb,ds,lane) *= 1/l[...]  UNCHANGED.
// ---------------------------------------------------------------------------
__global__ __launch_bounds__(256) void scalev_kernel(
    const float* __restrict__ l, __bf16* __restrict__ vp)
{
    int i = blockIdx.x * 256 + threadIdx.x;  // chunk index, 262144 total
    int lane = i & 63;
    int kb = (i >> 9) & 127;
    int b = i >> 16;
    int quad = lane >> 4;
    int k0 = kb * 32 + quad * 8;
    const float* lp = l + (size_t)b * N_ + k0;
    float4 a = *(const float4*)lp;
    float4 c = *(const float4*)(lp + 4);
    float r0 = __builtin_amdgcn_rcpf(a.x), r1 = __builtin_amdgcn_rcpf(a.y);
    float r2 = __builtin_amdgcn_rcpf(a.z), r3 = __builtin_amdgcn_rcpf(a.w);
    float r4 = __builtin_amdgcn_rcpf(c.x), r5 = __builtin_amdgcn_rcpf(c.y);
    float r6 = __builtin_amdgcn_rcpf(c.z), r7 = __builtin_amdgcn_rcpf(c.w);
    bf16x8 v = ((const bf16x8*)vp)[i];
    bf16x8 o;
    o[0] = (__bf16)((float)v[0] * r0); o[1] = (__bf16)((float)v[1] * r1);
    o[2] = (__bf16)((float)v[2] * r2); o[3] = (__bf16)((float)v[3] * r3);
    o[4] = (__bf16)((float)v[4] * r4); o[5] = (__bf16)((float)v[5] * r5);
    o[6] = (__bf16)((float)v[6] * r6); o[7] = (__bf16)((float)v[7] * r7);
    ((bf16x8*)vp)[i] = o;
}

// ---------------------------------------------------------------------------
// Kernel D: attention. s=4 wide-q loop (64 q/wave, 256 q/block), K/V tile
// via global_load_lds DMA double-buffer, XCD-bijective swizzle, KSEG=8.
// Epilogue: plain float4 stores to part (atomics removed — R2 showed 16.8M
// scalar atomics cost ~190 µs / 268 MB HBM write).
// grid = B * 16 * KSEG = 512 blocks of 256 (2 blocks/CU).
// ---------------------------------------------------------------------------
__global__ __launch_bounds__(256, 2) void attn_kernel(
    const __bf16* __restrict__ qp, const __bf16* __restrict__ kp,
    const __bf16* __restrict__ vp, float* __restrict__ part)
{
    __shared__ __bf16 lds[2][16 * 512];   // 2 x 16 KiB: chunks 0-7 K, 8-15 V

    // bijective swizzle: blocks with same (b,seg) land on one XCD (bid%8)
    int x = blockIdx.x;
    int xcd = x & 7;
    int i = x >> 3;                       // 0..63
    int group = xcd * 4 + (i & 3);        // 0..31 = (b,seg)
    int qtile = i >> 2;                   // 0..15 (256 q each)
    int b = group >> 3;
    int seg = group & 7;

    int w = threadIdx.x >> 6;
    int lane = threadIdx.x & 63;
    int quad = lane >> 4, l15 = lane & 15;

    const bf16x8* qc8 = (const bf16x8*)qp;
    const bf16x8* kc = (const bf16x8*)kp;
    const bf16x8* vc = (const bf16x8*)vp;

    int q0w = qtile * 256 + w * 64;       // this wave's 64 q rows
    int qstep0 = qtile * 16 + w * 4;
    bf16x8 bq[4][4];
#pragma unroll
    for (int s = 0; s < 4; ++s)
#pragma unroll
        for (int f = 0; f < 4; ++f)
            bq[s][f] = qc8[((size_t)(b * 256 + qstep0 + s) * 4 + f) * 64 + lane];

    f32x4 oacc[4][8];
#pragma unroll
    for (int s = 0; s < 4; ++s)
#pragma unroll
        for (int d = 0; d < 8; ++d) oacc[s][d] = (f32x4){0.f, 0.f, 0.f, 0.f};

    int kb0 = seg * 16;

    // prologue: DMA tile 0 (wave w stages chunks w*4..w*4+3)
#pragma unroll
    for (int ii = 0; ii < 4; ++ii) {
        int c = w * 4 + ii;
        const bf16x8* src = (c < 8) ? &kc[(((size_t)(b * 128 + kb0) * 8) + c) * 64 + lane]
                                    : &vc[(((size_t)(b * 128 + kb0) * 8) + (c - 8)) * 64 + lane];
        gload_lds16(src, &lds[0][c * 512]);
    }
    __syncthreads();

    for (int t = 0; t < 16; ++t) {
        __bf16* buf = &lds[t & 1][0];
        if (t + 1 < 16) {
            int kbn = kb0 + t + 1;
            __bf16* nbuf = &lds[(t + 1) & 1][0];
#pragma unroll
            for (int ii = 0; ii < 4; ++ii) {
                int c = w * 4 + ii;
                const bf16x8* src = (c < 8) ? &kc[(((size_t)(b * 128 + kbn) * 8) + c) * 64 + lane]
                                            : &vc[(((size_t)(b * 128 + kbn) * 8) + (c - 8)) * 64 + lane];
                gload_lds16(src, &nbuf[c * 512]);
            }
        }

        // QK^T + exp, per ab-half to cap register transients
        bf16x8 pb[4];
#pragma unroll
        for (int ab = 0; ab < 2; ++ab) {
            bf16x8 ak[4];
#pragma unroll
            for (int f = 0; f < 4; ++f)
                ak[f] = *(const bf16x8*)(buf + (f * 2 + ab) * 512 + lane * 8);
#pragma unroll
            for (int s = 0; s < 4; ++s) {
                f32x4 acc = {0.f, 0.f, 0.f, 0.f};
#pragma unroll
                for (int f = 0; f < 4; ++f)
                    acc = __builtin_amdgcn_mfma_f32_16x16x32_bf16(ak[f], bq[s][f], acc, 0, 0, 0);
#pragma unroll
                for (int r = 0; r < 4; ++r)
                    pb[s][ab * 4 + r] = (__bf16)__builtin_amdgcn_exp2f(acc[r]);
            }
        }
        // PV
#pragma unroll
        for (int ds = 0; ds < 8; ++ds) {
            bf16x8 vf = *(const bf16x8*)(buf + (8 + ds) * 512 + lane * 8);
#pragma unroll
            for (int s = 0; s < 4; ++s)
                oacc[s][ds] = __builtin_amdgcn_mfma_f32_16x16x32_bf16(
                    vf, pb[s], oacc[s][ds], 0, 0, 0);
        }
        __syncthreads();                  // tile t+1 landed; buf free for t+2
    }

    float* op = part + ((size_t)seg * B_ * N_ + (size_t)b * N_ + q0w) * D_;
#pragma unroll
    for (int s = 0; s < 4; ++s)
#pragma unroll
        for (int ds = 0; ds < 8; ++ds) {
            float4 o4;
            o4.x = oacc[s][ds][0]; o4.y = oacc[s][ds][1];
            o4.z = oacc[s][ds][2]; o4.w = oacc[s][ds][3];
            *(float4*)(op + (size_t)(s * 16 + l15) * D_ + ds * 16 + quad * 4) = o4;
        }
}

// ---------------------------------------------------------------------------
// Kernel E: out = sum of KSEG partials
// ---------------------------------------------------------------------------
__global__ __launch_bounds__(256) void reduce_kernel(
    const float* __restrict__ part, float* __restrict__ out)
{
    int i = blockIdx.x * 256 + threadIdx.x;
    const f32x4* p = (const f32x4*)part;
    f32x4 s = p[i];
#pragma unroll
    for (int sgi = 1; sgi < KSEG; ++sgi) {
        f32x4 t = p[(size_t)sgi * (B_ * N_ * D_ / 4) + i];
        s[0] += t[0]; s[1] += t[1]; s[2] += t[2]; s[3] += t[3];
    }
    ((f32x4*)out)[i] = s;
}

extern "C" void kernel_launch(void* const* d_in, const int* in_sizes, int n_in,
                              void* d_out, int out_size, void* d_ws, size_t ws_size,
                              hipStream_t stream) {
    const float* q = (const float*)d_in[0];
    const float* k = (const float*)d_in[1];
    const float* v = (const float*)d_in[2];
    float* out = (float*)d_out;
    char* ws = (char*)d_ws;
    __bf16* qp = (__bf16*)(ws);
    __bf16* kp = (__bf16*)(ws + OFF_KP);
    __bf16* vp = (__bf16*)(ws + OFF_VP);
    float* l    = (float*)(ws + OFF_L);
    float* part = (float*)(ws + OFF_PART);

    hipLaunchKernelGGL(cvt_kernel, dim3(2560), dim3(256), 0, stream, q, k, v, qp, kp, vp);
    hipMemsetAsync(l, 0, (size_t)B_ * N_ * sizeof(float), stream);
    hipLaunchKernelGGL(stats_kernel, dim3(B_ * 32 * QSEG), dim3(256), 0, stream, qp, kp, l);
    hipLaunchKernelGGL(scalev_kernel, dim3(1024), dim3(256), 0, stream, l, vp);
    hipLaunchKernelGGL(attn_kernel, dim3(B_ * 16 * KSEG), dim3(256), 0, stream, qp, kp, vp, part);
    hipLaunchKernelGGL(reduce_kernel, dim3(B_ * N_ * D_ / 4 / 256), dim3(256), 0, stream, part, out);
}

// Round 4
// 147.570 us; speedup vs baseline: 2.1914x; 1.0124x over previous
//
#include <hip/hip_runtime.h>
#include <hip/hip_bf16.h>

#define B_ 4
#define N_ 4096
#define D_ 128
#define KSEG 8
#define QSEG 8

typedef __bf16 bf16x8 __attribute__((ext_vector_type(8)));
typedef float f32x4 __attribute__((ext_vector_type(4)));

// alpha = log2(e) / sqrt(128), folded into Qp at conversion time
#define ALPHA 0.12752361680972262f

// ws layout (all fragment-linear packed, 16 B per (tile,frag,lane) chunk):
//   Qp : bf16 [B][256 qstep][4 f][64 lane][8]   @ 0      (4 MiB, alpha-scaled)
//   Kp : bf16 [B][128 kb][8 slot=f*2+ab][64][8] @ 4 MiB  (permuted-key frag order)
//   Vp : bf16 [B][128 kb][8 ds][64][8]          @ 8 MiB  (1/l folded in place)
//   l    : f32 [B][N]                           @ 12 MiB
//   part : f32 [KSEG][B][N][D]                  @ 13 MiB (64 MiB, KSEG=8)
#define OFF_KP   (4u << 20)
#define OFF_VP   (8u << 20)
#define OFF_L    (12u << 20)
#define OFF_PART (13u << 20)

// direct global->LDS DMA, 16 B per lane; LDS dest is wave-uniform base + lane*16
__device__ __forceinline__ void gload_lds16(const void* g, void* s) {
    __builtin_amdgcn_global_load_lds(
        (const __attribute__((address_space(1))) void*)g,
        (__attribute__((address_space(3))) void*)s, 16, 0, 0);
}

// ---------------------------------------------------------------------------
// Kernel A: pack Q*alpha, K (permuted key order), V-transpose into fragment-
// linear layouts. Blocks 2560..2575 additionally zero l (memset launch folded
// in; l is written by later kernels only, no ordering hazard within launch).
// ---------------------------------------------------------------------------
__global__ __launch_bounds__(256) void cvt_kernel(
    const float* __restrict__ q, const float* __restrict__ k,
    const float* __restrict__ v,
    __bf16* __restrict__ qp, __bf16* __restrict__ kp, __bf16* __restrict__ vp,
    float* __restrict__ l)
{
    __shared__ float vl[32 * 129];   // 16.5 KiB (V section only)

    int bid = blockIdx.x;
    int tid = threadIdx.x;
    if (bid < 2048) {
        int g = (bid & 1023) * 256 + tid;   // 0..262143 within section
        int lane = g & 63;
        int l15 = lane & 15, quad = lane >> 4;
        if (bid < 1024) {
            int f = (g >> 6) & 3;
            int qstep = (g >> 8) & 255;
            int b = g >> 16;
            const float* src = q + ((size_t)(b * N_ + qstep * 16 + l15) * D_ + (f * 4 + quad) * 8);
            float4 x0 = *(const float4*)src;
            float4 x1 = *(const float4*)(src + 4);
            bf16x8 y;
            y[0] = (__bf16)(x0.x * ALPHA); y[1] = (__bf16)(x0.y * ALPHA);
            y[2] = (__bf16)(x0.z * ALPHA); y[3] = (__bf16)(x0.w * ALPHA);
            y[4] = (__bf16)(x1.x * ALPHA); y[5] = (__bf16)(x1.y * ALPHA);
            y[6] = (__bf16)(x1.z * ALPHA); y[7] = (__bf16)(x1.w * ALPHA);
            ((bf16x8*)qp)[g] = y;
        } else {
            int slot = (g >> 6) & 7;
            int kb = (g >> 9) & 127;
            int b = g >> 16;
            int f = slot >> 1, ab = slot & 1;
            int row = kb * 32 + (l15 >> 2) * 8 + (l15 & 3) + ab * 4;
            const float* src = k + ((size_t)(b * N_ + row) * D_ + (f * 4 + quad) * 8);
            float4 x0 = *(const float4*)src;
            float4 x1 = *(const float4*)(src + 4);
            bf16x8 y;
            y[0] = (__bf16)x0.x; y[1] = (__bf16)x0.y; y[2] = (__bf16)x0.z; y[3] = (__bf16)x0.w;
            y[4] = (__bf16)x1.x; y[5] = (__bf16)x1.y; y[6] = (__bf16)x1.z; y[7] = (__bf16)x1.w;
            ((bf16x8*)kp)[g] = y;
        }
    } else if (bid < 2560) {
        int vb = bid - 2048;                // 0..511: one (b, kb) tile
        int b = vb >> 7, kb = vb & 127;
        const float4* src = (const float4*)(v + (size_t)(b * N_ + kb * 32) * D_);
#pragma unroll
        for (int rep = 0; rep < 4; ++rep) {
            int i = rep * 256 + tid;
            int row = i >> 5, c4 = i & 31;
            float4 x = src[row * 32 + c4];
            float* dst = &vl[row * 129 + c4 * 4];
            dst[0] = x.x; dst[1] = x.y; dst[2] = x.z; dst[3] = x.w;
        }
        __syncthreads();
#pragma unroll
        for (int rep = 0; rep < 2; ++rep) {
            int ci = rep * 256 + tid;       // 0..511
            int ds = ci >> 6, ln = ci & 63;
            int quad = ln >> 4, l15 = ln & 15;
            bf16x8 y;
#pragma unroll
            for (int j = 0; j < 8; ++j)
                y[j] = (__bf16)vl[(quad * 8 + j) * 129 + ds * 16 + l15];
            ((bf16x8*)vp)[(((size_t)(b * 128 + kb) * 8) + ds) * 64 + ln] = y;
        }
    } else {
        // zero l: 16 blocks x 256 threads x float4 = 16384 floats
        int i = (bid - 2560) * 256 + tid;
        ((f32x4*)l)[i] = (f32x4){0.f, 0.f, 0.f, 0.f};
    }
}

// ---------------------------------------------------------------------------
// Kernel B: column stats. Q-tile staging via global_load_lds. UNCHANGED.
// ---------------------------------------------------------------------------
__global__ __launch_bounds__(256, 4) void stats_kernel(
    const __bf16* __restrict__ qp, const __bf16* __restrict__ kp,
    float* __restrict__ l)
{
    __shared__ __bf16 lds[2][16 * 512];   // 2 x 16 KiB

    int idx = blockIdx.x;
    int qseg = idx & (QSEG - 1);
    int kb4 = (idx >> 3) & 31;
    int b = idx >> 8;
    int w = threadIdx.x >> 6;
    int lane = threadIdx.x & 63;
    int quad = lane >> 4, l15 = lane & 15;
    int kb = kb4 * 4 + w;

    const bf16x8* kc = (const bf16x8*)kp;
    const bf16x8* qc8 = (const bf16x8*)qp;

    bf16x8 af[2][4];
#pragma unroll
    for (int ab = 0; ab < 2; ++ab)
#pragma unroll
        for (int f = 0; f < 4; ++f)
            af[ab][f] = kc[(((size_t)(b * 128 + kb) * 8) + f * 2 + ab) * 64 + lane];

    int qs0 = qseg * 32;                  // 32 q-steps per segment, 8 iters of 4

    // prologue: DMA tile 0
#pragma unroll
    for (int f = 0; f < 4; ++f)
        gload_lds16(&qc8[((size_t)(b * 256 + qs0 + w) * 4 + f) * 64 + lane],
                    &lds[0][(w * 4 + f) * 512]);
    __syncthreads();

    float ps[8];
#pragma unroll
    for (int s = 0; s < 8; ++s) ps[s] = 0.f;

    for (int t = 0; t < 8; ++t) {
        __bf16* buf = &lds[t & 1][0];
        if (t + 1 < 8) {
            __bf16* nbuf = &lds[(t + 1) & 1][0];
#pragma unroll
            for (int f = 0; f < 4; ++f)
                gload_lds16(&qc8[((size_t)(b * 256 + qs0 + (t + 1) * 4 + w) * 4 + f) * 64 + lane],
                            &nbuf[(w * 4 + f) * 512]);
        }
#pragma unroll
        for (int j = 0; j < 4; ++j) {
            bf16x8 qf[4];
#pragma unroll
            for (int f = 0; f < 4; ++f)
                qf[f] = *(const bf16x8*)(buf + (j * 4 + f) * 512 + lane * 8);
#pragma unroll
            for (int ab = 0; ab < 2; ++ab) {
                f32x4 acc = {0.f, 0.f, 0.f, 0.f};
#pragma unroll
                for (int f = 0; f < 4; ++f)
                    acc = __builtin_amdgcn_mfma_f32_16x16x32_bf16(af[ab][f], qf[f], acc, 0, 0, 0);
#pragma unroll
                for (int r = 0; r < 4; ++r)
                    ps[ab * 4 + r] += __builtin_amdgcn_exp2f(acc[r]);
            }
        }
        __syncthreads();                  // next tile landed; buf free for t+2
    }
#pragma unroll
    for (int m = 1; m <= 8; m <<= 1)
#pragma unroll
        for (int s = 0; s < 8; ++s)
            ps[s] += __shfl_xor(ps[s], m, 64);
    if (l15 == 0) {
        // permuted C rows: key = kb*32 + quad*8 + ab*4 + r
        float* dst = l + (size_t)b * N_ + kb * 32 + quad * 8;
#pragma unroll
        for (int ab = 0; ab < 2; ++ab)
#pragma unroll
            for (int r = 0; r < 4; ++r)
                atomicAdd(dst + ab * 4 + r, ps[ab * 4 + r]);
    }
}

// ---------------------------------------------------------------------------
// Kernel C2: Vp chunk (b,kb,ds,lane) *= 1/l[...]  UNCHANGED.
// ---------------------------------------------------------------------------
__global__ __launch_bounds__(256) void scalev_kernel(
    const float* __restrict__ l, __bf16* __restrict__ vp)
{
    int i = blockIdx.x * 256 + threadIdx.x;  // chunk index, 262144 total
    int lane = i & 63;
    int kb = (i >> 9) & 127;
    int b = i >> 16;
    int quad = lane >> 4;
    int k0 = kb * 32 + quad * 8;
    const float* lp = l + (size_t)b * N_ + k0;
    float4 a = *(const float4*)lp;
    float4 c = *(const float4*)(lp + 4);
    float r0 = __builtin_amdgcn_rcpf(a.x), r1 = __builtin_amdgcn_rcpf(a.y);
    float r2 = __builtin_amdgcn_rcpf(a.z), r3 = __builtin_amdgcn_rcpf(a.w);
    float r4 = __builtin_amdgcn_rcpf(c.x), r5 = __builtin_amdgcn_rcpf(c.y);
    float r6 = __builtin_amdgcn_rcpf(c.z), r7 = __builtin_amdgcn_rcpf(c.w);
    bf16x8 v = ((const bf16x8*)vp)[i];
    bf16x8 o;
    o[0] = (__bf16)((float)v[0] * r0); o[1] = (__bf16)((float)v[1] * r1);
    o[2] = (__bf16)((float)v[2] * r2); o[3] = (__bf16)((float)v[3] * r3);
    o[4] = (__bf16)((float)v[4] * r4); o[5] = (__bf16)((float)v[5] * r5);
    o[6] = (__bf16)((float)v[6] * r6); o[7] = (__bf16)((float)v[7] * r7);
    ((bf16x8*)vp)[i] = o;
}

// ---------------------------------------------------------------------------
// Kernel D: attention. 512-thread blocks (8 waves), s=2 per wave (R9-proven
// inner loop), 256 q/block. grid = B*16*KSEG = 512 blocks = 2 blocks/CU
// -> 16 waves/CU = 4 waves/SIMD: two independent barrier groups per CU so
// one block computes while the other drains its DMA/barrier (R3 showed
// 2 waves/SIMD leaves the latency chain uncovered).
// Each wave stages 2 of 16 chunks/iter via global_load_lds.
// ---------------------------------------------------------------------------
__global__ __launch_bounds__(512, 4) void attn_kernel(
    const __bf16* __restrict__ qp, const __bf16* __restrict__ kp,
    const __bf16* __restrict__ vp, float* __restrict__ part)
{
    __shared__ __bf16 lds[2][16 * 512];   // 2 x 16 KiB: chunks 0-7 K, 8-15 V

    // bijective swizzle: blocks with same (b,seg) land on one XCD (bid%8)
    int x = blockIdx.x;
    int xcd = x & 7;
    int i = x >> 3;                       // 0..63
    int group = xcd * 4 + (i & 3);        // 0..31 = (b,seg)
    int qtile = i >> 2;                   // 0..15 (256 q each)
    int b = group >> 3;
    int seg = group & 7;

    int w = threadIdx.x >> 6;             // 0..7
    int lane = threadIdx.x & 63;
    int quad = lane >> 4, l15 = lane & 15;

    const bf16x8* qc8 = (const bf16x8*)qp;
    const bf16x8* kc = (const bf16x8*)kp;
    const bf16x8* vc = (const bf16x8*)vp;

    int q0w = qtile * 256 + w * 32;       // this wave's 32 q rows
    int qstep0 = qtile * 16 + w * 2;
    bf16x8 bq[2][4];
#pragma unroll
    for (int s = 0; s < 2; ++s)
#pragma unroll
        for (int f = 0; f < 4; ++f)
            bq[s][f] = qc8[((size_t)(b * 256 + qstep0 + s) * 4 + f) * 64 + lane];

    f32x4 oacc[2][8];
#pragma unroll
    for (int s = 0; s < 2; ++s)
#pragma unroll
        for (int d = 0; d < 8; ++d) oacc[s][d] = (f32x4){0.f, 0.f, 0.f, 0.f};

    int kb0 = seg * 16;

    // prologue: DMA tile 0 (wave w stages chunks 2w, 2w+1)
#pragma unroll
    for (int ii = 0; ii < 2; ++ii) {
        int c = w * 2 + ii;
        const bf16x8* src = (c < 8) ? &kc[(((size_t)(b * 128 + kb0) * 8) + c) * 64 + lane]
                                    : &vc[(((size_t)(b * 128 + kb0) * 8) + (c - 8)) * 64 + lane];
        gload_lds16(src, &lds[0][c * 512]);
    }
    __syncthreads();

    for (int t = 0; t < 16; ++t) {
        __bf16* buf = &lds[t & 1][0];
        if (t + 1 < 16) {
            int kbn = kb0 + t + 1;
            __bf16* nbuf = &lds[(t + 1) & 1][0];
#pragma unroll
            for (int ii = 0; ii < 2; ++ii) {
                int c = w * 2 + ii;
                const bf16x8* src = (c < 8) ? &kc[(((size_t)(b * 128 + kbn) * 8) + c) * 64 + lane]
                                            : &vc[(((size_t)(b * 128 + kbn) * 8) + (c - 8)) * 64 + lane];
                gload_lds16(src, &nbuf[c * 512]);
            }
        }

        bf16x8 akA[4], akB[4];
#pragma unroll
        for (int f = 0; f < 4; ++f) {
            akA[f] = *(const bf16x8*)(buf + (f * 2 + 0) * 512 + lane * 8);
            akB[f] = *(const bf16x8*)(buf + (f * 2 + 1) * 512 + lane * 8);
        }
        bf16x8 pb[2];
#pragma unroll
        for (int s = 0; s < 2; ++s) {
            f32x4 accA = {0.f, 0.f, 0.f, 0.f};
            f32x4 accB = {0.f, 0.f, 0.f, 0.f};
#pragma unroll
            for (int f = 0; f < 4; ++f) {
                accA = __builtin_amdgcn_mfma_f32_16x16x32_bf16(akA[f], bq[s][f], accA, 0, 0, 0);
                accB = __builtin_amdgcn_mfma_f32_16x16x32_bf16(akB[f], bq[s][f], accB, 0, 0, 0);
            }
            bf16x8 p;
            p[0] = (__bf16)__builtin_amdgcn_exp2f(accA[0]);
            p[1] = (__bf16)__builtin_amdgcn_exp2f(accA[1]);
            p[2] = (__bf16)__builtin_amdgcn_exp2f(accA[2]);
            p[3] = (__bf16)__builtin_amdgcn_exp2f(accA[3]);
            p[4] = (__bf16)__builtin_amdgcn_exp2f(accB[0]);
            p[5] = (__bf16)__builtin_amdgcn_exp2f(accB[1]);
            p[6] = (__bf16)__builtin_amdgcn_exp2f(accB[2]);
            p[7] = (__bf16)__builtin_amdgcn_exp2f(accB[3]);
            pb[s] = p;
        }
#pragma unroll
        for (int ds = 0; ds < 8; ++ds) {
            bf16x8 vf = *(const bf16x8*)(buf + (8 + ds) * 512 + lane * 8);
#pragma unroll
            for (int s = 0; s < 2; ++s)
                oacc[s][ds] = __builtin_amdgcn_mfma_f32_16x16x32_bf16(
                    vf, pb[s], oacc[s][ds], 0, 0, 0);
        }
        __syncthreads();                  // tile t+1 landed; buf free for t+2
    }

    float* op = part + ((size_t)seg * B_ * N_ + (size_t)b * N_ + q0w) * D_;
#pragma unroll
    for (int s = 0; s < 2; ++s)
#pragma unroll
        for (int ds = 0; ds < 8; ++ds) {
            float4 o4;
            o4.x = oacc[s][ds][0]; o4.y = oacc[s][ds][1];
            o4.z = oacc[s][ds][2]; o4.w = oacc[s][ds][3];
            *(float4*)(op + (size_t)(s * 16 + l15) * D_ + ds * 16 + quad * 4) = o4;
        }
}

// ---------------------------------------------------------------------------
// Kernel E: out = sum of KSEG partials
// ---------------------------------------------------------------------------
__global__ __launch_bounds__(256) void reduce_kernel(
    const float* __restrict__ part, float* __restrict__ out)
{
    int i = blockIdx.x * 256 + threadIdx.x;
    const f32x4* p = (const f32x4*)part;
    f32x4 s = p[i];
#pragma unroll
    for (int sgi = 1; sgi < KSEG; ++sgi) {
        f32x4 t = p[(size_t)sgi * (B_ * N_ * D_ / 4) + i];
        s[0] += t[0]; s[1] += t[1]; s[2] += t[2]; s[3] += t[3];
    }
    ((f32x4*)out)[i] = s;
}

extern "C" void kernel_launch(void* const* d_in, const int* in_sizes, int n_in,
                              void* d_out, int out_size, void* d_ws, size_t ws_size,
                              hipStream_t stream) {
    const float* q = (const float*)d_in[0];
    const float* k = (const float*)d_in[1];
    const float* v = (const float*)d_in[2];
    float* out = (float*)d_out;
    char* ws = (char*)d_ws;
    __bf16* qp = (__bf16*)(ws);
    __bf16* kp = (__bf16*)(ws + OFF_KP);
    __bf16* vp = (__bf16*)(ws + OFF_VP);
    float* l    = (float*)(ws + OFF_L);
    float* part = (float*)(ws + OFF_PART);

    hipLaunchKernelGGL(cvt_kernel, dim3(2576), dim3(256), 0, stream, q, k, v, qp, kp, vp, l);
    hipLaunchKernelGGL(stats_kernel, dim3(B_ * 32 * QSEG), dim3(256), 0, stream, qp, kp, l);
    hipLaunchKernelGGL(scalev_kernel, dim3(1024), dim3(256), 0, stream, l, vp);
    hipLaunchKernelGGL(attn_kernel, dim3(B_ * 16 * KSEG), dim3(512), 0, stream, qp, kp, vp, part);
    hipLaunchKernelGGL(reduce_kernel, dim3(B_ * N_ * D_ / 4 / 256), dim3(256), 0, stream, part, out);
}